// Round 1
// baseline (613.261 us; speedup 1.0000x reference)
//
#include <hip/hip_runtime.h>
#include <cstdint>
#include <cstddef>

#define MM 65536
#define NN 1024
#define KK 1024

typedef __bf16 bf16x8 __attribute__((ext_vector_type(8)));
typedef float f32x4 __attribute__((ext_vector_type(4)));

typedef const __attribute__((address_space(1))) unsigned int* gas_t;
typedef __attribute__((address_space(3))) unsigned int* las_t;

__device__ __forceinline__ void gll16(const void* g, void* l) {
  __builtin_amdgcn_global_load_lds((gas_t)g, (las_t)l, 16, 0, 0);
}

// exp2 for integer e in [-126, 127]
__device__ __forceinline__ float exp2i(int e) {
  return __int_as_float((e + 127) << 23);
}

// MXFP fake-quant (block=32 along last dim), fp32 -> exact bf16.
// One float4 per lane; 8 consecutive lanes = one 32-elem block.
__global__ __launch_bounds__(256) void mxfp_quant(const float* __restrict__ in,
                                                  unsigned short* __restrict__ out) {
  size_t i = (size_t)blockIdx.x * 256 + threadIdx.x;
  float4 v = ((const float4*)in)[i];
  float a = fmaxf(fmaxf(fabsf(v.x), fabsf(v.y)), fmaxf(fabsf(v.z), fabsf(v.w)));
  a = fmaxf(a, __shfl_xor(a, 1));
  a = fmaxf(a, __shfl_xor(a, 2));
  a = fmaxf(a, __shfl_xor(a, 4));
  // shared_exp = floor(log2(amax)) - EMAX(8); amax==0 -> use FP32_MIN_NORMAL (exp field 1)
  int ebits = (int)((__float_as_uint(a) >> 23) & 0xff);
  int se = (ebits > 0 ? ebits : 1) - 127 - 8;
  se = se < -126 ? -126 : se;  // ref clamps at -127; -126 only differs for impossible inputs
  float sinv = exp2i(-se);
  float sc = exp2i(se);

  float e[4] = {v.x, v.y, v.z, v.w};
  unsigned short o[4];
#pragma unroll
  for (int c = 0; c < 4; ++c) {
    float vv = e[c] * sinv;                                  // exact pow2 scale
    int pe = (int)((__float_as_uint(vv) >> 23) & 0xff) - 127; // floor(log2|vv|); zero->-127
    pe = pe < -6 ? -6 : pe;                                   // MIN_PEXP
    float r = floorf(fabsf(vv) * exp2i(6 - pe) + 0.5f);       // round away from zero
    float q = copysignf(r * exp2i(pe - 6), vv);
    q = fminf(fmaxf(q, -448.f), 448.f);
    float res = q * sc;                   // exactly representable in bf16 (<=8 sig bits)
    o[c] = (unsigned short)(__float_as_uint(res) >> 16);      // exact truncation
  }
  ushort4 ov = {o[0], o[1], o[2], o[3]};
  ((ushort4*)out)[i] = ov;
}

// C[m][n] = sum_k A[m][k]*B[n][k] + bias[n];  A: M x K bf16, B: N x K bf16, C fp32.
// 128x128 tile, BK=32, 256 threads (4 waves, 2x2 of 64x64), mfma_f32_16x16x32_bf16.
__global__ __launch_bounds__(256, 3) void gemm_bt(const unsigned short* __restrict__ A,
                                                  const unsigned short* __restrict__ B,
                                                  const float* __restrict__ bias,
                                                  float* __restrict__ C) {
  __shared__ unsigned short As[128 * 32];
  __shared__ unsigned short Bs[128 * 32];
  int t = threadIdx.x;
  int bx = blockIdx.x & 7;   // N tile (8 of them share one A tile at adjacent blockIdx)
  int by = blockIdx.x >> 3;  // M tile
  int m0 = by << 7, n0 = bx << 7;

  // staging: thread t covers LDS bytes [16t, 16t+16) = row t/4, 16B chunk t%4 (row=64B)
  int lr = t >> 2;
  int lc = (t & 3) << 4;
  const char* Ag = (const char*)A + (size_t)(m0 + lr) * (KK * 2) + lc;
  const char* Bg = (const char*)B + (size_t)(n0 + lr) * (KK * 2) + lc;
  char* AsB = (char*)As + t * 16;
  char* BsB = (char*)Bs + t * 16;

  int lane = t & 63, w = t >> 6;
  int wm = (w & 1) << 6, wn = (w >> 1) << 6;  // 64x64 per wave
  int quad = lane >> 4, r16 = lane & 15;

  f32x4 acc[4][4] = {};

  for (int kt = 0; kt < KK; kt += 32) {
    __syncthreads();  // previous compute done before overwrite
    size_t go = (size_t)kt * 2;
    gll16(Ag + go, AsB);
    gll16(Ag + go + (size_t)64 * KK * 2, AsB + 4096);
    gll16(Bg + go, BsB);
    gll16(Bg + go + (size_t)64 * KK * 2, BsB + 4096);
    __syncthreads();  // staging complete (vmcnt drain folded into barrier)

    bf16x8 af[4], bf[4];
#pragma unroll
    for (int i = 0; i < 4; ++i)
      af[i] = *(const bf16x8*)&As[(wm + i * 16 + r16) * 32 + quad * 8];
#pragma unroll
    for (int j = 0; j < 4; ++j)
      bf[j] = *(const bf16x8*)&Bs[(wn + j * 16 + r16) * 32 + quad * 8];
#pragma unroll
    for (int i = 0; i < 4; ++i)
#pragma unroll
      for (int j = 0; j < 4; ++j)
        acc[i][j] = __builtin_amdgcn_mfma_f32_16x16x32_bf16(af[i], bf[j], acc[i][j], 0, 0, 0);
  }

  // epilogue: C/D layout col=lane&15, row=quad*4+reg
  float bcol[4];
#pragma unroll
  for (int j = 0; j < 4; ++j) bcol[j] = bias[n0 + wn + j * 16 + r16];
#pragma unroll
  for (int i = 0; i < 4; ++i) {
    int rbase = m0 + wm + i * 16 + quad * 4;
#pragma unroll
    for (int j = 0; j < 4; ++j) {
      int col = n0 + wn + j * 16 + r16;
      float* Cp = C + (size_t)rbase * NN + col;
#pragma unroll
      for (int reg = 0; reg < 4; ++reg)
        Cp[(size_t)reg * NN] = acc[i][j][reg] + bcol[j];
    }
  }
}

extern "C" void kernel_launch(void* const* d_in, const int* in_sizes, int n_in,
                              void* d_out, int out_size, void* d_ws, size_t ws_size,
                              hipStream_t stream) {
  const float* x = (const float*)d_in[0];      // 8*8192*1024
  const float* wgt = (const float*)d_in[1];    // 1024*1024
  const float* bias = (const float*)d_in[2];   // 1024
  float* out = (float*)d_out;

  unsigned short* xq = (unsigned short*)d_ws;                  // 128 MB
  unsigned short* wq = xq + (size_t)MM * KK;                   // +2 MB

  mxfp_quant<<<(MM * (size_t)KK) / 1024, 256, 0, stream>>>(x, xq);    // 65536 blocks
  mxfp_quant<<<(NN * (size_t)KK) / 1024, 256, 0, stream>>>(wgt, wq);  // 1024 blocks
  gemm_bt<<<(MM / 128) * (NN / 128), 256, 0, stream>>>(xq, wq, bias, out);
}